// Round 1
// baseline (139.410 us; speedup 1.0000x reference)
//
#include <hip/hip_runtime.h>
#include <stdint.h>

#define NQ 12
#define DIM 4096
#define NLAYERS 6
#define TPB 256
#define PER_T (DIM / TPB)        // 16 amplitudes per thread
#define PAIRS_PER_T (DIM / 2 / TPB)  // 8 gate pairs per thread

// d_ws layout (floats):
//   [0 .. 575]      gate matrices: (l*12+w)*8 -> m00r,m00i,m01r,m01i,m10r,m10i,m11r,m11i
//   [576 .. 647]    per-layer composed CNOT masks (uint32): l*12 + bit
//   [1024 .. 5119]  coef[4096] = b + sum_w W[w]*(bit_w ? -1 : +1)

__global__ __launch_bounds__(256) void setup_kernel(
    const float* __restrict__ weights,   // [6,12,3]
    const float* __restrict__ W,         // [1,12]
    const float* __restrict__ bptr,      // [1]
    float* __restrict__ ws)
{
    int tid = threadIdx.x;

    // --- 72 Rot gate matrices ---
    if (tid < NLAYERS * NQ) {
        int l = tid / NQ, w = tid % NQ;
        float phi   = weights[(l * NQ + w) * 3 + 0];
        float theta = weights[(l * NQ + w) * 3 + 1];
        float omega = weights[(l * NQ + w) * 3 + 2];
        float st, ct; sincosf(0.5f * theta, &st, &ct);
        float sp, cp; sincosf(0.5f * (phi + omega), &sp, &cp);  // ep = cp - i*sp
        float sm, cm; sincosf(0.5f * (phi - omega), &sm, &cm);  // em = cm + i*sm
        float* g = ws + tid * 8;
        g[0] =  cp * ct;  g[1] = -sp * ct;   // m00 = ep*ct
        g[2] = -cm * st;  g[3] = -sm * st;   // m01 = -em*st
        g[4] =  cm * st;  g[5] = -sm * st;   // m10 = conj(em)*st
        g[6] =  cp * ct;  g[7] =  sp * ct;   // m11 = conj(ep)*ct
    }

    // --- composed CNOT permutation masks per layer ---
    // src(dst) = T_{w=0}(T_{w=1}(...T_{w=11}(dst)...)), each T linear over GF(2)
    if (tid >= 72 && tid < 72 + NLAYERS) {
        int l = tid - 72;
        int r = l % (NQ - 1) + 1;
        uint32_t* pm = (uint32_t*)(ws + 576) + l * NQ;
        for (int p = 0; p < NQ; p++) {
            uint32_t v = 1u << p;
            for (int w = NQ - 1; w >= 0; w--) {
                int pc = NQ - 1 - w;
                int pt = NQ - 1 - ((w + r) % NQ);
                v ^= ((v >> pc) & 1u) << pt;
            }
            pm[p] = v;
        }
    }

    // --- expectation coefficients (b folded in; sum(probs)=1) ---
    float bv = bptr[0];
    for (int i = tid; i < DIM; i += TPB) {
        float acc = bv;
        #pragma unroll
        for (int w = 0; w < NQ; w++)
            acc += W[w] * (((i >> (NQ - 1 - w)) & 1) ? -1.0f : 1.0f);
        ws[1024 + i] = acc;
    }
}

__global__ __launch_bounds__(256) void qsim_kernel(
    const float* __restrict__ x,    // [512,12]
    const float* __restrict__ ws,
    float* __restrict__ out)        // [512]
{
    __shared__ float sre[DIM];
    __shared__ float sim[DIM];
    __shared__ float cs[2 * NQ];
    __shared__ float redbuf[4];

    const int tid = threadIdx.x;
    const int b   = blockIdx.x;

    // per-batch RY angles
    if (tid < NQ) {
        float s, c;
        sincosf(0.5f * x[b * NQ + tid], &s, &c);
        cs[tid] = c;           // wire w, |0> amplitude
        cs[NQ + tid] = s;      // wire w, |1> amplitude
    }
    __syncthreads();

    // --- product-state init (real): amp[i] = prod_w (bit_{11-w}(i) ? s_w : c_w) ---
    // i = tid + j*256: bits 0..7 from tid, bits 8..11 from j
    float base = 1.0f;
    #pragma unroll
    for (int p = 0; p < 8; p++) {
        int w = NQ - 1 - p;
        base *= ((tid >> p) & 1) ? cs[NQ + w] : cs[w];
    }
    #pragma unroll
    for (int j = 0; j < PER_T; j++) {
        float hi = 1.0f;
        #pragma unroll
        for (int p = 8; p < NQ; p++) {
            int w = NQ - 1 - p;
            hi *= ((j >> (p - 8)) & 1) ? cs[NQ + w] : cs[w];
        }
        int i = tid + j * TPB;
        sre[i] = base * hi;
        sim[i] = 0.0f;
    }
    __syncthreads();

    for (int l = 0; l < NLAYERS; l++) {
        // --- 12 Rot gates ---
        #pragma unroll
        for (int w = 0; w < NQ; w++) {
            const float* g = ws + (l * NQ + w) * 8;
            float m00r = g[0], m00i = g[1], m01r = g[2], m01i = g[3];
            float m10r = g[4], m10i = g[5], m11r = g[6], m11i = g[7];
            const int p = NQ - 1 - w;
            const int lowmask = (1 << p) - 1;
            #pragma unroll
            for (int it = 0; it < PAIRS_PER_T; it++) {
                int t  = tid + it * TPB;
                int i0 = ((t >> p) << (p + 1)) | (t & lowmask);
                int i1 = i0 | (1 << p);
                float a0r = sre[i0], a0i = sim[i0];
                float a1r = sre[i1], a1i = sim[i1];
                sre[i0] = m00r * a0r - m00i * a0i + m01r * a1r - m01i * a1i;
                sim[i0] = m00r * a0i + m00i * a0r + m01r * a1i + m01i * a1r;
                sre[i1] = m10r * a0r - m10i * a0i + m11r * a1r - m11i * a1i;
                sim[i1] = m10r * a0i + m10i * a0r + m11r * a1i + m11i * a1r;
            }
            __syncthreads();
        }

        // --- whole-layer CNOT network as one linear permutation pass ---
        const uint32_t* pm = (const uint32_t*)(ws + 576) + l * NQ;
        uint32_t m[NQ];
        #pragma unroll
        for (int p = 0; p < NQ; p++) m[p] = pm[p];

        uint32_t srcLow = 0;
        #pragma unroll
        for (int p = 0; p < 8; p++)
            srcLow ^= ((tid >> p) & 1) ? m[p] : 0u;

        float tr[PER_T], ti[PER_T];
        #pragma unroll
        for (int j = 0; j < PER_T; j++) {
            uint32_t src = srcLow;
            #pragma unroll
            for (int p = 8; p < NQ; p++)
                src ^= ((j >> (p - 8)) & 1) ? m[p] : 0u;
            tr[j] = sre[src];
            ti[j] = sim[src];
        }
        __syncthreads();
        #pragma unroll
        for (int j = 0; j < PER_T; j++) {
            int dst = tid + j * TPB;
            sre[dst] = tr[j];
            sim[dst] = ti[j];
        }
        __syncthreads();
    }

    // --- expectation: out[b] = sum_i |amp[i]|^2 * coef[i]  (b, W folded into coef) ---
    const float* coef = ws + 1024;
    float acc = 0.0f;
    #pragma unroll
    for (int j = 0; j < PER_T; j++) {
        int i = tid + j * TPB;
        float r = sre[i], q = sim[i];
        acc += (r * r + q * q) * coef[i];
    }
    #pragma unroll
    for (int off = 32; off > 0; off >>= 1)
        acc += __shfl_down(acc, off, 64);
    if ((tid & 63) == 0) redbuf[tid >> 6] = acc;
    __syncthreads();
    if (tid == 0)
        out[b] = redbuf[0] + redbuf[1] + redbuf[2] + redbuf[3];
}

extern "C" void kernel_launch(void* const* d_in, const int* in_sizes, int n_in,
                              void* d_out, int out_size, void* d_ws, size_t ws_size,
                              hipStream_t stream) {
    const float* x       = (const float*)d_in[0];   // [512,12]
    const float* weights = (const float*)d_in[1];   // [6,12,3]
    const float* W       = (const float*)d_in[2];   // [1,12]
    const float* bptr    = (const float*)d_in[3];   // [1]
    float* out = (float*)d_out;
    float* ws  = (float*)d_ws;

    setup_kernel<<<1, TPB, 0, stream>>>(weights, W, bptr, ws);
    qsim_kernel<<<512, TPB, 0, stream>>>(x, ws, out);
}

// Round 2
// 112.384 us; speedup vs baseline: 1.2405x; 1.2405x over previous
//
#include <hip/hip_runtime.h>
#include <stdint.h>
#include <utility>

#define NQ 12
#define DIM 4096
#define NLAYERS 6
#define TPB 256
#define NGATES (NLAYERS * NQ)

// ---------------------------------------------------------------------------
// Compile-time circuit algebra.
// Logical index i (bit p <-> wire w = 11-p). Stored index k = B(i), B linear
// over GF(2). Rotation on wire w => generalized pair gate on stored array:
//   flip mask  f = B e_p          (partner k ^ f)
//   selector   s = row_p(B^-1)    (role = parity(k & s); parity(f&s)=1)
// CNOT layer A_l (index map, verified convention from round-1 kernel):
//   B <- B * A_l ,  B^-1 <- A_l^-1 * B^-1
// A bit-permutation pi re-labels stored bits; applied to all masks at the end.
// New-bit roles: 0..3 = per-thread register, 4..9 = lane, 10..11 = wave.
// ---------------------------------------------------------------------------
struct CK_t {
    uint32_t f[NGATES];
    uint32_t s[NGATES];
    uint32_t frow[NQ];     // rows of final B^-1 (permuted)
    uint32_t wnp[NQ];      // new bit position -> wire (11 - orig bit pos)
    int nC;                // # cross-wave gates (diagnostic)
};

constexpr CK_t build_ck() {
    CK_t ck{};
    uint32_t Bcol[NQ]{}, Icol[NQ]{};          // columns of B and B^-1
    for (int q = 0; q < NQ; q++) { Bcol[q] = 1u << q; Icol[q] = 1u << q; }
    uint32_t fraw[NGATES]{}, sraw[NGATES]{};

    for (int l = 0; l < NLAYERS; l++) {
        for (int w = 0; w < NQ; w++) {
            int p = NQ - 1 - w;
            fraw[l * NQ + w] = Bcol[p];
            uint32_t s = 0;
            for (int q = 0; q < NQ; q++) s |= ((Icol[q] >> p) & 1u) << q;
            sraw[l * NQ + w] = s;
        }
        int r = l % (NQ - 1) + 1;
        uint32_t Acol[NQ]{}, Aicol[NQ]{};
        for (int q = 0; q < NQ; q++) {
            uint32_t v = 1u << q;
            for (int w = NQ - 1; w >= 0; w--) {            // A = T0∘T1∘...∘T11
                int pc = NQ - 1 - w, pt = NQ - 1 - ((w + r) % NQ);
                v ^= ((v >> pc) & 1u) << pt;
            }
            Acol[q] = v;
            uint32_t u = 1u << q;
            for (int w = 0; w < NQ; w++) {                 // A^-1 = T11∘...∘T0
                int pc = NQ - 1 - w, pt = NQ - 1 - ((w + r) % NQ);
                u ^= ((u >> pc) & 1u) << pt;
            }
            Aicol[q] = u;
        }
        uint32_t Bn[NQ]{}, In[NQ]{};
        for (int q = 0; q < NQ; q++) {
            uint32_t acc = 0, a = Acol[q];
            for (int k = 0; k < NQ; k++) if ((a >> k) & 1u) acc ^= Bcol[k];
            Bn[q] = acc;
            uint32_t acc2 = 0, bq = Icol[q];
            for (int k = 0; k < NQ; k++) if ((bq >> k) & 1u) acc2 ^= Aicol[k];
            In[q] = acc2;
        }
        for (int q = 0; q < NQ; q++) { Bcol[q] = Bn[q]; Icol[q] = In[q]; }
    }
    uint32_t frraw[NQ]{};
    for (int p = 0; p < NQ; p++) {
        uint32_t s = 0;
        for (int q = 0; q < NQ; q++) s |= ((Icol[q] >> p) & 1u) << q;
        frraw[p] = s;
    }

    // --- choose 2 wave bits minimizing # gates whose f touches them ---
    int ba = 0, bb = 1, bc = 100000;
    for (int a = 0; a < NQ; a++)
        for (int b = a + 1; b < NQ; b++) {
            uint32_t m = (1u << a) | (1u << b);
            int c = 0;
            for (int g = 0; g < NGATES; g++) c += (fraw[g] & m) ? 1 : 0;
            if (c < bc) { bc = c; ba = a; bb = b; }
        }
    uint32_t wmask = (1u << ba) | (1u << bb);

    // --- among remaining 10 bits choose 4 local bits maximizing pure-register gates ---
    int rem[10]{}; int nr = 0;
    for (int q = 0; q < NQ; q++) if (!((wmask >> q) & 1u)) rem[nr++] = q;
    int bi[4] = {rem[0], rem[1], rem[2], rem[3]}; int bestA = -1;
    for (int i0 = 0; i0 < 10; i0++)
     for (int i1 = i0 + 1; i1 < 10; i1++)
      for (int i2 = i1 + 1; i2 < 10; i2++)
       for (int i3 = i2 + 1; i3 < 10; i3++) {
           uint32_t lm = (1u<<rem[i0])|(1u<<rem[i1])|(1u<<rem[i2])|(1u<<rem[i3]);
           int c = 0;
           for (int g = 0; g < NGATES; g++)
               if (!(fraw[g] & wmask) && !(fraw[g] & (~lm & 0xFFFu))) c++;
           if (c > bestA) { bestA = c; bi[0]=rem[i0]; bi[1]=rem[i1]; bi[2]=rem[i2]; bi[3]=rem[i3]; }
       }
    uint32_t lmask = (1u<<bi[0])|(1u<<bi[1])|(1u<<bi[2])|(1u<<bi[3]);

    uint32_t pos[NQ]{};                      // orig bit -> new bit
    for (int i = 0; i < 4; i++) pos[bi[i]] = (uint32_t)i;
    pos[ba] = 10; pos[bb] = 11;
    {
        uint32_t nn = 4;
        for (int q = 0; q < NQ; q++)
            if (!(((wmask | lmask) >> q) & 1u)) pos[q] = nn++;
    }
    for (int q = 0; q < NQ; q++) ck.wnp[pos[q]] = (uint32_t)(NQ - 1 - q);

    for (int g = 0; g < NGATES; g++) {
        uint32_t f = 0, s = 0;
        for (int q = 0; q < NQ; q++) {
            f |= ((fraw[g] >> q) & 1u) << pos[q];
            s |= ((sraw[g] >> q) & 1u) << pos[q];
        }
        ck.f[g] = f; ck.s[g] = s;
        if (f >> 10) ck.nC++;
    }
    for (int p = 0; p < NQ; p++) {
        uint32_t s = 0;
        for (int q = 0; q < NQ; q++) s |= ((frraw[p] >> q) & 1u) << pos[q];
        ck.frow[p] = s;
    }
    return ck;
}

constexpr CK_t CK = build_ck();

// gate matrix: float4 = (m00r, m00i, m01r, m01i); m11 = conj(m00), m10 = (-m01r, m01i)
__device__ __forceinline__ void apply1(float& re, float& im, float ore, float oim,
                                       float4 m, uint32_t sgn) {
    // role=1 (sgn=0x80000000): ma=(m00r,-m00i)=m11, mb=(-m01r,m01i)=m10
    float fai = __uint_as_float(__float_as_uint(m.y) ^ sgn);
    float fbr = __uint_as_float(__float_as_uint(m.z) ^ sgn);
    float nre = m.x * re - fai * im + fbr * ore - m.w * oim;
    float nim = m.x * im + fai * re + fbr * oim + m.w * ore;
    re = nre; im = nim;
}

template <int G>
__device__ __forceinline__ void do_gate(float (&RE)[16], float (&IM)[16],
                                        const float4* smat, float2* xb, int tid) {
    constexpr uint32_t f  = CK.f[G];
    constexpr uint32_t s  = CK.s[G];
    constexpr int      fl = (int)(f & 15u);
    constexpr int      ft = (int)(f >> 4);       // thread-bit part (lane+wave)
    constexpr bool     isC = (f >> 10) != 0;

    float4 m = smat[G];
    uint32_t sgn_t = (uint32_t)(__popc(tid & (int)(s >> 4)) & 1) << 31;

    if constexpr (isC) {
        // cross-wave: exchange full 16-amp vectors through LDS (conflict-free)
        __syncthreads();                                // protect previous use of xb
        #pragma unroll
        for (int l = 0; l < 16; l++) xb[l * TPB + tid] = make_float2(RE[l], IM[l]);
        __syncthreads();
        float ore[16], oim[16];
        #pragma unroll
        for (int l = 0; l < 16; l++) {
            float2 o = xb[(l ^ fl) * TPB + (tid ^ ft)];
            ore[l] = o.x; oim[l] = o.y;
        }
        #pragma unroll
        for (int l = 0; l < 16; l++) {
            uint32_t sg = sgn_t ^ ((uint32_t)(__popc(l & (int)(s & 15u)) & 1) << 31);
            apply1(RE[l], IM[l], ore[l], oim[l], m, sg);
        }
    } else if constexpr (ft != 0) {
        // within-wave: shfl_xor, no barrier
        if constexpr (fl == 0) {
            #pragma unroll
            for (int l = 0; l < 16; l++) {
                float ore = __shfl_xor(RE[l], ft, 64);
                float oim = __shfl_xor(IM[l], ft, 64);
                uint32_t sg = sgn_t ^ ((uint32_t)(__popc(l & (int)(s & 15u)) & 1) << 31);
                apply1(RE[l], IM[l], ore, oim, m, sg);
            }
        } else {
            #pragma unroll
            for (int l = 0; l < 16; l++) {
                constexpr int dummy = 0; (void)dummy;
                int l2 = l ^ fl;
                if (l2 < l) continue;                   // each pair once
                float o0re = __shfl_xor(RE[l2], ft, 64);
                float o0im = __shfl_xor(IM[l2], ft, 64);
                float o1re = __shfl_xor(RE[l],  ft, 64);
                float o1im = __shfl_xor(IM[l],  ft, 64);
                uint32_t sg0 = sgn_t ^ ((uint32_t)(__popc(l  & (int)(s & 15u)) & 1) << 31);
                uint32_t sg1 = sgn_t ^ ((uint32_t)(__popc(l2 & (int)(s & 15u)) & 1) << 31);
                apply1(RE[l],  IM[l],  o0re, o0im, m, sg0);
                apply1(RE[l2], IM[l2], o1re, o1im, m, sg1);
            }
        }
    } else {
        // pure-register gate (f local only; fl != 0 since f != 0)
        #pragma unroll
        for (int l = 0; l < 16; l++) {
            int l2 = l ^ fl;
            if (l2 < l) continue;
            float o0re = RE[l2], o0im = IM[l2];
            float o1re = RE[l],  o1im = IM[l];
            uint32_t sg0 = sgn_t ^ ((uint32_t)(__popc(l  & (int)(s & 15u)) & 1) << 31);
            uint32_t sg1 = sgn_t ^ ((uint32_t)(__popc(l2 & (int)(s & 15u)) & 1) << 31);
            apply1(RE[l],  IM[l],  o0re, o0im, m, sg0);
            apply1(RE[l2], IM[l2], o1re, o1im, m, sg1);
        }
    }
}

template <int... Gs>
__device__ __forceinline__ void run_gates(std::integer_sequence<int, Gs...>,
                                          float (&RE)[16], float (&IM)[16],
                                          const float4* smat, float2* xb, int tid) {
    (do_gate<Gs>(RE, IM, smat, xb, tid), ...);
}

__global__ __launch_bounds__(TPB) void qsim_kernel(
    const float* __restrict__ x,        // [512,12]
    const float* __restrict__ weights,  // [6,12,3]
    const float* __restrict__ Wp,       // [12]
    const float* __restrict__ bptr,     // [1]
    float* __restrict__ out)            // [512]
{
    __shared__ float2 xb[16 * TPB];     // 32 KB exchange buffer
    __shared__ float4 smat[NGATES];     // gate matrices (m00, m01)
    __shared__ float  scs[NQ], sss[NQ];
    __shared__ float  red[4];

    const int tid = threadIdx.x;
    const int b   = blockIdx.x;

    // per-block setup: RY angles + 72 gate matrices
    if (tid < NQ) {
        float s_, c_;
        sincosf(0.5f * x[b * NQ + tid], &s_, &c_);
        scs[tid] = c_; sss[tid] = s_;
    }
    if (tid < NGATES) {
        float phi   = weights[tid * 3 + 0];
        float theta = weights[tid * 3 + 1];
        float omega = weights[tid * 3 + 2];
        float st, ct; sincosf(0.5f * theta, &st, &ct);
        float sp, cp; sincosf(0.5f * (phi + omega), &sp, &cp);
        float sm, cm; sincosf(0.5f * (phi - omega), &sm, &cm);
        smat[tid] = make_float4(cp * ct, -sp * ct, -cm * st, -sm * st);
    }
    __syncthreads();

    // product-state init: stored k = (tid<<4)|loc; bit np of k <-> wire CK.wnp[np]
    float base = 1.0f;
    #pragma unroll
    for (int np = 4; np < NQ; np++) {
        int w = (int)CK.wnp[np];
        base *= ((tid >> (np - 4)) & 1) ? sss[w] : scs[w];
    }
    float RE[16], IM[16];
    #pragma unroll
    for (int l = 0; l < 16; l++) {
        float a = base;
        #pragma unroll
        for (int np = 0; np < 4; np++) {
            int w = (int)CK.wnp[np];
            a *= ((l >> np) & 1) ? sss[w] : scs[w];
        }
        RE[l] = a; IM[l] = 0.0f;
    }

    // all 72 generalized gates, fully unrolled with compile-time masks
    run_gates(std::make_integer_sequence<int, NGATES>{}, RE, IM, smat, xb, tid);

    // expectation: coef(k) = b + sum_p W[11-p] * (1 - 2*parity(k & frow[p]))
    const float bv = bptr[0];
    float wb[NQ];
    #pragma unroll
    for (int p = 0; p < NQ; p++) {
        uint32_t row = CK.frow[p];
        int tp = __popc(tid & (int)(row >> 4)) & 1;
        float Wv = Wp[NQ - 1 - p];
        wb[p] = tp ? -Wv : Wv;
    }
    float acc = 0.0f;
    #pragma unroll
    for (int l = 0; l < 16; l++) {
        float coef = bv;
        #pragma unroll
        for (int p = 0; p < NQ; p++)
            coef += (__popc(l & (int)(CK.frow[p] & 15u)) & 1) ? -wb[p] : wb[p];
        acc += (RE[l] * RE[l] + IM[l] * IM[l]) * coef;
    }
    #pragma unroll
    for (int off = 32; off > 0; off >>= 1)
        acc += __shfl_down(acc, off, 64);
    if ((tid & 63) == 0) red[tid >> 6] = acc;
    __syncthreads();
    if (tid == 0) out[b] = red[0] + red[1] + red[2] + red[3];
}

extern "C" void kernel_launch(void* const* d_in, const int* in_sizes, int n_in,
                              void* d_out, int out_size, void* d_ws, size_t ws_size,
                              hipStream_t stream) {
    const float* x       = (const float*)d_in[0];
    const float* weights = (const float*)d_in[1];
    const float* W       = (const float*)d_in[2];
    const float* bptr    = (const float*)d_in[3];
    qsim_kernel<<<512, TPB, 0, stream>>>(x, weights, W, bptr, (float*)d_out);
}

// Round 3
// 102.172 us; speedup vs baseline: 1.3645x; 1.0999x over previous
//
#include <hip/hip_runtime.h>
#include <stdint.h>

#define NQ 12
#define DIM 4096
#define NLAYERS 6
#define TPB 256

// ---------------------------------------------------------------------------
// Storage basis = identity at the start of every layer's rotations:
//   stored index k = logical index i; bit p of k <-> wire w = 11-p.
//   bits 0..3  -> per-thread register amps (free gates, compile-time signs)
//   bits 4..9  -> lane bits               (shfl_xor gates)
//   bits 10,11 -> wave bits               (fused into the per-layer LDS pass)
// Per layer l: ONE LDS pass reads src = A_{l-1}(k ^ flips) (A_{-1} = I),
// applying the previous CNOT network re-base AND the two wave-bit rotations
// (wires 0,1) as a 4-term complex combination. Then 6 lane gates + 4 register
// gates. Layer 5's CNOT network is folded into the expectation coefficients
// via rows of A_5^{-1}.
// LDS layout is bit-transposed: slot(k) = ((k&15)<<8) | (k>>4)  (linear over
// GF(2) => composed with the pass map at compile time; reads cost 1 XOR).
// ---------------------------------------------------------------------------
struct CK_t {
    uint32_t SM[NLAYERS][NQ];   // slot-mapped columns of pass map M_l = A_{l-1}
    uint32_t frow[NQ];          // rows of A_5^{-1} (for expectation coefs)
};

constexpr uint32_t slotmap(uint32_t k) { return ((k & 15u) << 8) | (k >> 4); }

constexpr CK_t build_ck() {
    CK_t ck{};
    uint32_t Mcol[NQ];
    for (int q = 0; q < NQ; q++) Mcol[q] = 1u << q;          // M_0 = I
    for (int l = 0; l < NLAYERS; l++) {
        for (int q = 0; q < NQ; q++) ck.SM[l][q] = slotmap(Mcol[q]);
        int r = l % (NQ - 1) + 1;
        uint32_t Acol[NQ]{}, Aicol[NQ]{};
        for (int q = 0; q < NQ; q++) {
            uint32_t v = 1u << q;
            for (int w = NQ - 1; w >= 0; w--) {              // A = T0∘T1∘...∘T11
                int pc = NQ - 1 - w, pt = NQ - 1 - ((w + r) % NQ);
                v ^= ((v >> pc) & 1u) << pt;
            }
            Acol[q] = v;
            uint32_t u = 1u << q;
            for (int w = 0; w < NQ; w++) {                   // A^-1
                int pc = NQ - 1 - w, pt = NQ - 1 - ((w + r) % NQ);
                u ^= ((u >> pc) & 1u) << pt;
            }
            Aicol[q] = u;
        }
        for (int q = 0; q < NQ; q++) Mcol[q] = Acol[q];      // next pass map
        if (l == NLAYERS - 1) {
            for (int p = 0; p < NQ; p++) {
                uint32_t s = 0;
                for (int q = 0; q < NQ; q++) s |= ((Aicol[q] >> p) & 1u) << q;
                ck.frow[p] = s;
            }
        }
    }
    return ck;
}
constexpr CK_t CK = build_ck();

__device__ __forceinline__ float sxor(float v, uint32_t s) {
    return __uint_as_float(__float_as_uint(v) ^ s);
}

// Fused pass: re-base by A_{L-1} + rotations on wires 1 (bit 10) and 0 (bit 11)
template<int L>
__device__ __forceinline__ void do_pass(float (&RE)[16], float (&IM)[16],
                                        const float4* smat, float2* xb, int tid) {
    float2* buf = xb + ((L & 1) ? DIM : 0);
    float2* wrow = buf + tid;
    #pragma unroll
    for (int l = 0; l < 16; l++) wrow[l << 8] = make_float2(RE[l], IM[l]);

    // wave-gate coefficients: a = bit10(k) = tid bit 6, b = bit11(k) = tid bit 7
    float4 m1 = smat[L * NQ + 1];   // wire 1 -> bit 10 (da)
    float4 m0 = smat[L * NQ + 0];   // wire 0 -> bit 11 (db)
    uint32_t sa = (uint32_t)((tid >> 6) & 1) << 31;
    uint32_t sb = (uint32_t)((tid >> 7) & 1) << 31;
    // M[r][r]   = (mx,  my) | r=1: (mx, -my)
    // M[r][r^1] = (mz,  mw) | r=1: (-mz, mw)
    float A0r = m1.x,           A0i = sxor(m1.y, sa);
    float A1r = sxor(m1.z, sa), A1i = m1.w;
    float B0r = m0.x,           B0i = sxor(m0.y, sb);
    float B1r = sxor(m0.z, sb), B1i = m0.w;
    float c00r = A0r*B0r - A0i*B0i, c00i = A0r*B0i + A0i*B0r;
    float c01r = A0r*B1r - A0i*B1i, c01i = A0r*B1i + A0i*B1r;
    float c10r = A1r*B0r - A1i*B0i, c10i = A1r*B0i + A1i*B0r;
    float c11r = A1r*B1r - A1i*B1i, c11i = A1r*B1i + A1i*B1r;

    // thread part of slot-mapped src index
    uint32_t srcT = 0;
    #pragma unroll
    for (int j = 0; j < 8; j++)
        srcT ^= ((tid >> j) & 1) ? CK.SM[L][4 + j] : 0u;

    __syncthreads();

    #pragma unroll
    for (int l = 0; l < 16; l++) {
        uint32_t C00 = 0;
        #pragma unroll
        for (int q = 0; q < 4; q++)
            if ((l >> q) & 1) C00 ^= CK.SM[L][q];           // folds: l,q literal
        uint32_t i00 = srcT ^ C00;
        uint32_t i10 = i00 ^ CK.SM[L][10];
        uint32_t i01 = i00 ^ CK.SM[L][11];
        uint32_t i11 = i10 ^ CK.SM[L][11];
        float2 s00 = buf[i00], s10 = buf[i10], s01 = buf[i01], s11 = buf[i11];
        float nr = c00r*s00.x - c00i*s00.y;
        float ni = c00r*s00.y + c00i*s00.x;
        nr += c10r*s10.x - c10i*s10.y;  ni += c10r*s10.y + c10i*s10.x;
        nr += c01r*s01.x - c01i*s01.y;  ni += c01r*s01.y + c01i*s01.x;
        nr += c11r*s11.x - c11i*s11.y;  ni += c11r*s11.y + c11i*s11.x;
        RE[l] = nr; IM[l] = ni;
    }
}

template<int L, int W>  // wires 2..7 -> bits 9..4 (lane bits)
__device__ __forceinline__ void lane_gate(float (&RE)[16], float (&IM)[16],
                                          const float4* smat, int tid) {
    constexpr int q  = NQ - 1 - W;       // 4..9
    constexpr int lm = 1 << (q - 4);     // lane xor mask
    float4 m = smat[L * NQ + W];
    uint32_t sgn = (uint32_t)((tid >> (q - 4)) & 1) << 31;
    float fai = sxor(m.y, sgn), fbr = sxor(m.z, sgn);
    #pragma unroll
    for (int l = 0; l < 16; l++) {
        float orr = __shfl_xor(RE[l], lm, 64);
        float oii = __shfl_xor(IM[l], lm, 64);
        float nr = m.x*RE[l] - fai*IM[l] + fbr*orr - m.w*oii;
        float ni = m.x*IM[l] + fai*RE[l] + fbr*oii + m.w*orr;
        RE[l] = nr; IM[l] = ni;
    }
}

template<int L, int W>  // wires 8..11 -> bits 3..0 (register bits)
__device__ __forceinline__ void reg_gate(float (&RE)[16], float (&IM)[16],
                                         const float4* smat) {
    constexpr int q = NQ - 1 - W;        // 0..3
    float4 m = smat[L * NQ + W];
    #pragma unroll
    for (int l = 0; l < 16; l++) {
        if (l & (1 << q)) continue;
        int l2 = l | (1 << q);
        float a0r = RE[l], a0i = IM[l], a1r = RE[l2], a1i = IM[l2];
        RE[l]  = m.x*a0r - m.y*a0i + m.z*a1r - m.w*a1i;   // role 0
        IM[l]  = m.x*a0i + m.y*a0r + m.z*a1i + m.w*a1r;
        RE[l2] = m.x*a1r + m.y*a1i - m.z*a0r - m.w*a0i;   // role 1 (signs folded)
        IM[l2] = m.x*a1i - m.y*a1r - m.z*a0i + m.w*a0r;
    }
}

template<int L>
__device__ __forceinline__ void do_layer(float (&RE)[16], float (&IM)[16],
                                         const float4* smat, float2* xb, int tid) {
    do_pass<L>(RE, IM, smat, xb, tid);
    lane_gate<L, 2>(RE, IM, smat, tid);
    lane_gate<L, 3>(RE, IM, smat, tid);
    lane_gate<L, 4>(RE, IM, smat, tid);
    lane_gate<L, 5>(RE, IM, smat, tid);
    lane_gate<L, 6>(RE, IM, smat, tid);
    lane_gate<L, 7>(RE, IM, smat, tid);
    reg_gate<L, 8>(RE, IM, smat);
    reg_gate<L, 9>(RE, IM, smat);
    reg_gate<L, 10>(RE, IM, smat);
    reg_gate<L, 11>(RE, IM, smat);
}

__global__ __launch_bounds__(TPB) void qsim_kernel(
    const float* __restrict__ x,        // [512,12]
    const float* __restrict__ weights,  // [6,12,3]
    const float* __restrict__ Wp,       // [12]
    const float* __restrict__ bptr,     // [1]
    float* __restrict__ out)            // [512]
{
    __shared__ float2 xb[2 * DIM];      // 64 KB double-buffered exchange
    __shared__ float4 smat[NLAYERS * NQ];
    __shared__ float  scs[NQ], sss[NQ];
    __shared__ float  red[4];

    const int tid = threadIdx.x;
    const int b   = blockIdx.x;

    if (tid < NQ) {
        float s_, c_;
        sincosf(0.5f * x[b * NQ + tid], &s_, &c_);
        scs[tid] = c_; sss[tid] = s_;
    }
    if (tid < NLAYERS * NQ) {
        float phi   = weights[tid * 3 + 0];
        float theta = weights[tid * 3 + 1];
        float omega = weights[tid * 3 + 2];
        float st, ct; sincosf(0.5f * theta, &st, &ct);
        float sp, cp; sincosf(0.5f * (phi + omega), &sp, &cp);
        float sm, cm; sincosf(0.5f * (phi - omega), &sm, &cm);
        smat[tid] = make_float4(cp * ct, -sp * ct, -cm * st, -sm * st);
    }
    __syncthreads();

    // product-state init (identity basis): k = (tid<<4)|l, bit p <-> wire 11-p
    float base = 1.0f;
    #pragma unroll
    for (int p = 4; p < NQ; p++) {
        int w = NQ - 1 - p;
        base *= ((tid >> (p - 4)) & 1) ? sss[w] : scs[w];
    }
    float RE[16], IM[16];
    #pragma unroll
    for (int l = 0; l < 16; l++) {
        float a = base;
        #pragma unroll
        for (int p = 0; p < 4; p++) {
            int w = NQ - 1 - p;
            a *= ((l >> p) & 1) ? sss[w] : scs[w];
        }
        RE[l] = a; IM[l] = 0.0f;
    }

    do_layer<0>(RE, IM, smat, xb, tid);
    do_layer<1>(RE, IM, smat, xb, tid);
    do_layer<2>(RE, IM, smat, xb, tid);
    do_layer<3>(RE, IM, smat, xb, tid);
    do_layer<4>(RE, IM, smat, xb, tid);
    do_layer<5>(RE, IM, smat, xb, tid);

    // expectation: logical i = A_5^{-1}(k); coef = b + sum_p W[11-p]*(1-2*bit_p(i))
    const float bv = bptr[0];
    float wb[NQ];
    #pragma unroll
    for (int p = 0; p < NQ; p++) {
        uint32_t row = CK.frow[p];
        int tp = __popc(tid & (int)(row >> 4)) & 1;
        float Wv = Wp[NQ - 1 - p];
        wb[p] = tp ? -Wv : Wv;
    }
    float acc = 0.0f;
    #pragma unroll
    for (int l = 0; l < 16; l++) {
        float coef = bv;
        #pragma unroll
        for (int p = 0; p < NQ; p++)
            coef += (__popc(l & (int)(CK.frow[p] & 15u)) & 1) ? -wb[p] : wb[p];
        acc += (RE[l] * RE[l] + IM[l] * IM[l]) * coef;
    }
    #pragma unroll
    for (int off = 32; off > 0; off >>= 1)
        acc += __shfl_down(acc, off, 64);
    if ((tid & 63) == 0) red[tid >> 6] = acc;
    __syncthreads();
    if (tid == 0) out[b] = red[0] + red[1] + red[2] + red[3];
}

extern "C" void kernel_launch(void* const* d_in, const int* in_sizes, int n_in,
                              void* d_out, int out_size, void* d_ws, size_t ws_size,
                              hipStream_t stream) {
    const float* x       = (const float*)d_in[0];
    const float* weights = (const float*)d_in[1];
    const float* W       = (const float*)d_in[2];
    const float* bptr    = (const float*)d_in[3];
    qsim_kernel<<<512, TPB, 0, stream>>>(x, weights, W, bptr, (float*)d_out);
}

// Round 4
// 98.809 us; speedup vs baseline: 1.4109x; 1.0340x over previous
//
#include <hip/hip_runtime.h>
#include <stdint.h>

#define NQ 12
#define DIM 4096
#define NLAYERS 6
#define TPB 256

// ---------------------------------------------------------------------------
// All 72 rotations become REGISTER gates (compile-time flip mask + signs).
// Index bits of stored k: 0..3 register-local, 4..9 lane (tid 0..5),
// 10,11 wave (tid 6,7). Per layer (basis = identity at entry):
//   C1: wires 11,10,9,8 (logical bits 0..3, local)     - 4 reg gates
//   pass2: gather G2 = swap bits{0-3}<->{8-11}          - 1 src/amp, rank-4 ok
//   C2: wires 3,2,1,0 (logical 8..11 now local)         - 4 reg gates
//   pass3: gather G3 = swap bits{0-3}<->{4-7}           - 1 src/amp, rank-2
//          (uses layout Lpr to keep writes conflict-free; reads ~4x conflicted
//           - structurally unavoidable: pulling 4 lane bits leaves <4 lane rows)
//   C3: wires 7,6,5,4 (logical 4..7 now local)          - 4 reg gates
//   pass1 (next layer): gather G1 = pi'^-1 o A_l  -> identity basis + CNOT
// Layer 0 skips pass1 (init already identity). Layer 5's pending CNOT A_5 is
// folded into expectation coefficient rows (frow).
// Storage layouts: Lstd slot=((k&15)<<8)|(k>>4) (passes 1,2);
// Lpr routes k bits {6..9} to slot 0..3 (pass 3) so its writes stay rank-4.
// ---------------------------------------------------------------------------
struct CK_t {
    uint32_t RC1[NLAYERS][NQ];   // pass1 read cols (layers 1..5)
    uint32_t RC2[NQ];
    uint32_t RC3[NQ];
    uint32_t frow[NQ];           // rows of A5^-1 o pi' (epilogue signs)
};

constexpr uint32_t G2f(uint32_t k){ return ((k&15u)<<8) | (k&0xF0u) | ((k>>8)&15u); }
constexpr uint32_t G3f(uint32_t k){ return ((k&15u)<<4) | ((k>>4)&15u) | (k&0xF00u); }
constexpr uint32_t Lstd(uint32_t k){ return ((k&15u)<<8) | (k>>4); }
constexpr uint32_t Lpr(uint32_t k){ return ((k>>6)&15u) | (((k>>4)&3u)<<4) | (((k>>10)&3u)<<6) | ((k&15u)<<8); }

constexpr CK_t build_ck() {
    CK_t ck{};
    uint32_t Acols[NLAYERS][NQ]{}, Aicol5[NQ]{};
    for (int l = 0; l < NLAYERS; l++) {
        int r = l % (NQ - 1) + 1;
        for (int q = 0; q < NQ; q++) {
            uint32_t v = 1u << q;
            for (int w = NQ - 1; w >= 0; w--) {          // A = T0∘T1∘...∘T11
                int pc = NQ - 1 - w, pt = NQ - 1 - ((w + r) % NQ);
                v ^= ((v >> pc) & 1u) << pt;
            }
            Acols[l][q] = v;
            if (l == NLAYERS - 1) {
                uint32_t u = 1u << q;
                for (int w = 0; w < NQ; w++) {           // A^-1
                    int pc = NQ - 1 - w, pt = NQ - 1 - ((w + r) % NQ);
                    u ^= ((u >> pc) & 1u) << pt;
                }
                Aicol5[q] = u;
            }
        }
    }
    for (int j = 0; j < NQ; j++) ck.RC2[j] = Lstd(G2f(1u << j));
    for (int j = 0; j < NQ; j++) ck.RC3[j] = Lpr(G3f(1u << j));
    // pass1 of layer l: gather G1 = pi'^-1 ∘ A_{l-1};  pi'^-1(v) = G3(G2(v))
    for (int l = 1; l < NLAYERS; l++)
        for (int j = 0; j < NQ; j++)
            ck.RC1[l][j] = Lstd(G3f(G2f(Acols[l - 1][j])));
    // epilogue: output logical index i(k) = A5^-1( pi'(k) ), pi'(v)=G2(G3(v))
    uint32_t Mcol[NQ]{};
    for (int j = 0; j < NQ; j++) {
        uint32_t pj = G2f(G3f(1u << j));
        uint32_t M = 0;
        for (int m = 0; m < NQ; m++) if ((pj >> m) & 1u) M ^= Aicol5[m];
        Mcol[j] = M;
    }
    for (int p = 0; p < NQ; p++) {
        uint32_t s = 0;
        for (int j = 0; j < NQ; j++) s |= ((Mcol[j] >> p) & 1u) << j;
        ck.frow[p] = s;
    }
    return ck;
}
constexpr CK_t CK = build_ck();

// KIND: 1 = rebase (Lstd), 2 = swap 0-3/8-11 (Lstd), 3 = swap 0-3/4-7 (Lpr)
template<int KIND, int L, int PAR>
__device__ __forceinline__ void do_pass(float (&RE)[16], float (&IM)[16],
                                        float2* xb, int tid) {
    float2* buf = xb + PAR * DIM;
    int wbase;
    if constexpr (KIND == 3) wbase = (int)Lpr((uint32_t)tid << 4);
    else                     wbase = tid;
    #pragma unroll
    for (int l = 0; l < 16; l++)
        buf[wbase + (l << 8)] = make_float2(RE[l], IM[l]);

    uint32_t srcT = 0;
    #pragma unroll
    for (int j = 0; j < 8; j++) {
        uint32_t c = (KIND == 1) ? CK.RC1[L][4 + j]
                   : (KIND == 2) ? CK.RC2[4 + j] : CK.RC3[4 + j];
        srcT ^= ((tid >> j) & 1) ? c : 0u;
    }
    __syncthreads();
    #pragma unroll
    for (int l = 0; l < 16; l++) {
        uint32_t C = 0;
        #pragma unroll
        for (int q = 0; q < 4; q++)
            if ((l >> q) & 1)
                C ^= (KIND == 1) ? CK.RC1[L][q]
                   : (KIND == 2) ? CK.RC2[q] : CK.RC3[q];
        float2 v = buf[srcT ^ C];
        RE[l] = v.x; IM[l] = v.y;
    }
}

// rotation on wire W, register-local bit Q; signs fully folded.
// m = (m00r, m00i, m01r, m01i); m10 = (-m.z, m.w), m11 = (m.x, -m.y)
template<int L, int W, int Q>
__device__ __forceinline__ void reg_gate(float (&RE)[16], float (&IM)[16],
                                         const float4* smat) {
    float4 m = smat[L * NQ + W];
    #pragma unroll
    for (int l = 0; l < 16; l++) {
        if (l & (1 << Q)) continue;
        int l2 = l | (1 << Q);
        float a0r = RE[l], a0i = IM[l], a1r = RE[l2], a1i = IM[l2];
        RE[l]  = m.x * a0r - m.y * a0i + m.z * a1r - m.w * a1i;
        IM[l]  = m.x * a0i + m.y * a0r + m.z * a1i + m.w * a1r;
        RE[l2] = m.x * a1r + m.y * a1i - m.z * a0r - m.w * a0i;
        IM[l2] = m.x * a1i - m.y * a1r - m.z * a0i + m.w * a0r;
    }
}

template<int L>
__device__ __forceinline__ void do_layer(float (&RE)[16], float (&IM)[16],
                                         const float4* smat, float2* xb, int tid) {
    if constexpr (L > 0)
        do_pass<1, L, (3 * L - 1) & 1>(RE, IM, xb, tid);
    reg_gate<L, 11, 0>(RE, IM, smat);
    reg_gate<L, 10, 1>(RE, IM, smat);
    reg_gate<L,  9, 2>(RE, IM, smat);
    reg_gate<L,  8, 3>(RE, IM, smat);
    do_pass<2, L, (3 * L) & 1>(RE, IM, xb, tid);
    reg_gate<L, 3, 0>(RE, IM, smat);
    reg_gate<L, 2, 1>(RE, IM, smat);
    reg_gate<L, 1, 2>(RE, IM, smat);
    reg_gate<L, 0, 3>(RE, IM, smat);
    do_pass<3, L, (3 * L + 1) & 1>(RE, IM, xb, tid);
    reg_gate<L, 7, 0>(RE, IM, smat);
    reg_gate<L, 6, 1>(RE, IM, smat);
    reg_gate<L, 5, 2>(RE, IM, smat);
    reg_gate<L, 4, 3>(RE, IM, smat);
}

__global__ __launch_bounds__(TPB) void qsim_kernel(
    const float* __restrict__ x,        // [512,12]
    const float* __restrict__ weights,  // [6,12,3]
    const float* __restrict__ Wp,       // [12]
    const float* __restrict__ bptr,     // [1]
    float* __restrict__ out)            // [512]
{
    __shared__ float2 xb[2 * DIM];      // 64 KB double-buffered exchange
    __shared__ float4 smat[NLAYERS * NQ];
    __shared__ float  scs[NQ], sss[NQ];
    __shared__ float  red[4];

    const int tid = threadIdx.x;
    const int b   = blockIdx.x;

    if (tid < NQ) {
        float s_, c_;
        sincosf(0.5f * x[b * NQ + tid], &s_, &c_);
        scs[tid] = c_; sss[tid] = s_;
    }
    if (tid < NLAYERS * NQ) {
        float phi   = weights[tid * 3 + 0];
        float theta = weights[tid * 3 + 1];
        float omega = weights[tid * 3 + 2];
        float st, ct; sincosf(0.5f * theta, &st, &ct);
        float sp, cp; sincosf(0.5f * (phi + omega), &sp, &cp);
        float sm, cm; sincosf(0.5f * (phi - omega), &sm, &cm);
        smat[tid] = make_float4(cp * ct, -sp * ct, -cm * st, -sm * st);
    }
    __syncthreads();

    // product-state init, identity basis: k = (tid<<4)|l, bit p <-> wire 11-p
    float base = 1.0f;
    #pragma unroll
    for (int p = 4; p < NQ; p++) {
        int w = NQ - 1 - p;
        base *= ((tid >> (p - 4)) & 1) ? sss[w] : scs[w];
    }
    float RE[16], IM[16];
    #pragma unroll
    for (int l = 0; l < 16; l++) {
        float a = base;
        #pragma unroll
        for (int p = 0; p < 4; p++) {
            int w = NQ - 1 - p;
            a *= ((l >> p) & 1) ? sss[w] : scs[w];
        }
        RE[l] = a; IM[l] = 0.0f;
    }

    do_layer<0>(RE, IM, smat, xb, tid);
    do_layer<1>(RE, IM, smat, xb, tid);
    do_layer<2>(RE, IM, smat, xb, tid);
    do_layer<3>(RE, IM, smat, xb, tid);
    do_layer<4>(RE, IM, smat, xb, tid);
    do_layer<5>(RE, IM, smat, xb, tid);

    // expectation: i(k) = A5^-1(pi'(k)); coef = b + sum_p W[11-p]*(1-2*bit_p(i))
    const float bv = bptr[0];
    float wb[NQ];
    #pragma unroll
    for (int p = 0; p < NQ; p++) {
        uint32_t row = CK.frow[p];
        int tp = __popc(tid & (int)(row >> 4)) & 1;
        float Wv = Wp[NQ - 1 - p];
        wb[p] = tp ? -Wv : Wv;
    }
    float acc = 0.0f;
    #pragma unroll
    for (int l = 0; l < 16; l++) {
        float coef = bv;
        #pragma unroll
        for (int p = 0; p < NQ; p++)
            coef += (__popc(l & (int)(CK.frow[p] & 15u)) & 1) ? -wb[p] : wb[p];
        acc += (RE[l] * RE[l] + IM[l] * IM[l]) * coef;
    }
    #pragma unroll
    for (int off = 32; off > 0; off >>= 1)
        acc += __shfl_down(acc, off, 64);
    if ((tid & 63) == 0) red[tid >> 6] = acc;
    __syncthreads();
    if (tid == 0) out[b] = red[0] + red[1] + red[2] + red[3];
}

extern "C" void kernel_launch(void* const* d_in, const int* in_sizes, int n_in,
                              void* d_out, int out_size, void* d_ws, size_t ws_size,
                              hipStream_t stream) {
    const float* x       = (const float*)d_in[0];
    const float* weights = (const float*)d_in[1];
    const float* W       = (const float*)d_in[2];
    const float* bptr    = (const float*)d_in[3];
    qsim_kernel<<<512, TPB, 0, stream>>>(x, weights, W, bptr, (float*)d_out);
}

// Round 5
// 93.105 us; speedup vs baseline: 1.4973x; 1.0613x over previous
//
#include <hip/hip_runtime.h>
#include <stdint.h>

#define NQ 12
#define DIM 4096
#define NLAYERS 6
#define TPB 256

typedef float v2f __attribute__((ext_vector_type(2)));

// ---------------------------------------------------------------------------
// Same circuit algebra as round 4 (all 72 rotations are register gates, 17
// GF(2)-linear gather passes), but every pass gets a CUSTOM conflict-free LDS
// layout Lambda built at compile time:
//   write addr = Lambda(k),  read addr = Lambda(M(k)).
//   Bank rows (slot bits 0..3) are chosen greedily so they have full rank on
//   the lane quarter-span {e4..e7} AND on its M-image {M(e4)..M(e7)} => each
//   16-lane quarter of every b64 access hits 16 distinct bank pairs (the
//   empirically conflict-free pattern). Guaranteed to exist for bijective M.
// Gates operate on v2f (re,im) pairs -> v_pk_fma_f32 packed math.
// ---------------------------------------------------------------------------
struct Pass_t {
    uint32_t WT[8];    // Lambda columns for thread bits (k bits 4..11)
    uint32_t WL[16];   // Lambda image of local nibble l
    uint32_t RT[8];    // (Lambda o M) columns for thread bits
    uint32_t RL[16];   // (Lambda o M) image of local nibble l
};
struct CK_t {
    Pass_t PG2, PG3;       // shared layouts for the fixed window-swap passes
    Pass_t P1[NLAYERS];    // per-layer rebase passes (index 1..5 used)
    uint32_t frow[NQ];     // epilogue sign rows
};

constexpr uint32_t G2f(uint32_t k){ return ((k&15u)<<8) | (k&0xF0u) | ((k>>8)&15u); }
constexpr uint32_t G3f(uint32_t k){ return ((k&15u)<<4) | ((k>>4)&15u) | (k&0xF00u); }

constexpr uint32_t ech_reduce(const uint32_t* v, int n, uint32_t x){
    bool ch = true;
    while (ch) {
        ch = false;
        for (int i = 0; i < n; i++)
            if (v[i] && (x ^ v[i]) < x) { x ^= v[i]; ch = true; }
    }
    return x;
}

constexpr Pass_t build_pass(const uint32_t* Mc) {
    Pass_t P{};
    uint32_t rows[12]{}; int nr = 0;
    // --- greedy bank rows: rank 4 on {e4..e7} and on {Mc[4]..Mc[7]} ---
    {
        uint32_t e1[4]{}, e2[4]{}; int n1 = 0, n2 = 0;
        // candidate order: singles, then pairs, then triples (cheap hits first)
        for (int step = 0; step < 4; step++) {
            bool found = false;
            for (int pc = 1; pc <= 3 && !found; pc++) {
                for (int a = 0; a < 12 && !found; a++)
                for (int b = (pc >= 2 ? a + 1 : 12); (pc >= 2 ? b < 12 : b == 12) && !found; b++)
                for (int c = (pc == 3 ? b + 1 : 12); (pc == 3 ? c < 12 : c == 12) && !found; c++) {
                    uint32_t m = (1u << a);
                    if (pc >= 2) m |= (1u << b);
                    if (pc == 3) m |= (1u << c);
                    uint32_t v1 = (m >> 4) & 15u;
                    uint32_t v2 = 0;
                    for (int j = 0; j < 4; j++)
                        v2 |= (uint32_t)(__builtin_popcount(m & Mc[4 + j]) & 1) << j;
                    uint32_t r1 = ech_reduce(e1, n1, v1);
                    uint32_t r2 = ech_reduce(e2, n2, v2);
                    if (r1 && r2) {
                        rows[nr++] = m; e1[n1++] = r1; e2[n2++] = r2; found = true;
                    }
                }
            }
            if (!found) { rows[nr] = 1u << (4 + nr); nr++; }   // fallback (degraded)
        }
    }
    // --- complete to an invertible 12x12 ---
    {
        uint32_t ef[12]{}; int nf = 0;
        for (int i = 0; i < nr; i++) {
            uint32_t r = ech_reduce(ef, nf, rows[i]);
            if (r) ef[nf++] = r;
        }
        for (uint32_t m = 1; m < 4096u && nr < 12; m++) {
            uint32_t r = ech_reduce(ef, nf, m);
            if (r) { rows[nr++] = m; ef[nf++] = r; }
        }
    }
    // --- columns of Lambda and Lambda o M ---
    uint32_t col[12]{}, rc[12]{};
    for (int j = 0; j < 12; j++) {
        uint32_t c = 0;
        for (int i = 0; i < 12; i++) c |= (uint32_t)((rows[i] >> j) & 1u) << i;
        col[j] = c;
    }
    for (int j = 0; j < 12; j++) {
        uint32_t a = 0, mc = Mc[j];
        for (int q = 0; q < 12; q++) if ((mc >> q) & 1u) a ^= col[q];
        rc[j] = a;
    }
    for (int j = 0; j < 8; j++) { P.WT[j] = col[4 + j]; P.RT[j] = rc[4 + j]; }
    for (int l = 0; l < 16; l++) {
        uint32_t aw = 0, ar = 0;
        for (int q = 0; q < 4; q++) if ((l >> q) & 1) { aw ^= col[q]; ar ^= rc[q]; }
        P.WL[l] = aw; P.RL[l] = ar;
    }
    return P;
}

constexpr CK_t build_ck() {
    CK_t ck{};
    uint32_t Acols[NLAYERS][NQ]{}, Aicol5[NQ]{};
    for (int l = 0; l < NLAYERS; l++) {
        int r = l % (NQ - 1) + 1;
        for (int q = 0; q < NQ; q++) {
            uint32_t v = 1u << q;
            for (int w = NQ - 1; w >= 0; w--) {            // A = T0∘T1∘...∘T11
                int pc = NQ - 1 - w, pt = NQ - 1 - ((w + r) % NQ);
                v ^= ((v >> pc) & 1u) << pt;
            }
            Acols[l][q] = v;
            if (l == NLAYERS - 1) {
                uint32_t u = 1u << q;
                for (int w = 0; w < NQ; w++) {             // A^-1
                    int pc = NQ - 1 - w, pt = NQ - 1 - ((w + r) % NQ);
                    u ^= ((u >> pc) & 1u) << pt;
                }
                Aicol5[q] = u;
            }
        }
    }
    uint32_t McG2[12]{}, McG3[12]{}, Mc1[12]{};
    for (int j = 0; j < 12; j++) { McG2[j] = G2f(1u << j); McG3[j] = G3f(1u << j); }
    ck.PG2 = build_pass(McG2);
    ck.PG3 = build_pass(McG3);
    for (int l = 1; l < NLAYERS; l++) {
        for (int j = 0; j < 12; j++) Mc1[j] = G3f(G2f(Acols[l - 1][j]));
        ck.P1[l] = build_pass(Mc1);
    }
    // epilogue: i(k) = A5^-1(pi'(k)), pi'(v) = G2(G3(v))
    uint32_t Mcol[NQ]{};
    for (int j = 0; j < NQ; j++) {
        uint32_t pj = G2f(G3f(1u << j));
        uint32_t M = 0;
        for (int m = 0; m < NQ; m++) if ((pj >> m) & 1u) M ^= Aicol5[m];
        Mcol[j] = M;
    }
    for (int p = 0; p < NQ; p++) {
        uint32_t s = 0;
        for (int j = 0; j < NQ; j++) s |= ((Mcol[j] >> p) & 1u) << j;
        ck.frow[p] = s;
    }
    return ck;
}
constexpr CK_t CK = build_ck();

// KIND: 1 = layer rebase, 2 = swap 0-3/8-11, 3 = swap 0-3/4-7
template<int KIND, int L, int PAR>
__device__ __forceinline__ void do_pass(v2f (&Z)[16], v2f* xb, int tid) {
    constexpr Pass_t P = (KIND == 1) ? CK.P1[L] : (KIND == 2) ? CK.PG2 : CK.PG3;
    v2f* buf = xb + PAR * DIM;
    uint32_t comb = 0;
    #pragma unroll
    for (int j = 0; j < 8; j++) {
        uint32_t pk = P.WT[j] | (P.RT[j] << 16);
        comb ^= (uint32_t)(-(int)((tid >> j) & 1)) & pk;
    }
    uint32_t wbase = comb & 0xFFFu, rbase = comb >> 16;
    #pragma unroll
    for (int l = 0; l < 16; l++)
        buf[wbase ^ P.WL[l]] = Z[l];
    __syncthreads();
    #pragma unroll
    for (int l = 0; l < 16; l++)
        Z[l] = buf[rbase ^ P.RL[l]];
}

// rotation on wire W at register-local bit Q; m = (m00r, m00i, m01r, m01i),
// m10 = -m.z + i*m.w, m11 = m.x - i*m.y.  J(z) = (-z.y, z.x) => packed fma.
template<int L, int W, int Q>
__device__ __forceinline__ void reg_gate(v2f (&Z)[16], const float4* smat) {
    float4 m = smat[L * NQ + W];
    #pragma unroll
    for (int l = 0; l < 16; l++) {
        if (l & (1 << Q)) continue;
        int l2 = l | (1 << Q);
        v2f z0 = Z[l], z1 = Z[l2];
        v2f j0 = { -z0.y, z0.x };
        v2f j1 = { -z1.y, z1.x };
        Z[l]  = m.x * z0 + m.y * j0 + m.z * z1 + m.w * j1;
        Z[l2] = m.x * z1 - m.y * j1 - m.z * z0 + m.w * j0;
    }
}

template<int L>
__device__ __forceinline__ void do_layer(v2f (&Z)[16], const float4* smat,
                                         v2f* xb, int tid) {
    if constexpr (L > 0)
        do_pass<1, L, (3 * L - 1) & 1>(Z, xb, tid);
    reg_gate<L, 11, 0>(Z, smat);
    reg_gate<L, 10, 1>(Z, smat);
    reg_gate<L,  9, 2>(Z, smat);
    reg_gate<L,  8, 3>(Z, smat);
    do_pass<2, L, (3 * L) & 1>(Z, xb, tid);
    reg_gate<L, 3, 0>(Z, smat);
    reg_gate<L, 2, 1>(Z, smat);
    reg_gate<L, 1, 2>(Z, smat);
    reg_gate<L, 0, 3>(Z, smat);
    do_pass<3, L, (3 * L + 1) & 1>(Z, xb, tid);
    reg_gate<L, 7, 0>(Z, smat);
    reg_gate<L, 6, 1>(Z, smat);
    reg_gate<L, 5, 2>(Z, smat);
    reg_gate<L, 4, 3>(Z, smat);
}

__global__ __launch_bounds__(TPB) void qsim_kernel(
    const float* __restrict__ x,        // [512,12]
    const float* __restrict__ weights,  // [6,12,3]
    const float* __restrict__ Wp,       // [12]
    const float* __restrict__ bptr,     // [1]
    float* __restrict__ out)            // [512]
{
    __shared__ v2f    xb[2 * DIM];      // 64 KB double-buffered exchange
    __shared__ float4 smat[NLAYERS * NQ];
    __shared__ float  scs[NQ], sss[NQ];
    __shared__ float  red[4];

    const int tid = threadIdx.x;
    const int b   = blockIdx.x;

    if (tid < NQ) {
        float s_, c_;
        sincosf(0.5f * x[b * NQ + tid], &s_, &c_);
        scs[tid] = c_; sss[tid] = s_;
    }
    if (tid < NLAYERS * NQ) {
        float phi   = weights[tid * 3 + 0];
        float theta = weights[tid * 3 + 1];
        float omega = weights[tid * 3 + 2];
        float st, ct; sincosf(0.5f * theta, &st, &ct);
        float sp, cp; sincosf(0.5f * (phi + omega), &sp, &cp);
        float sm, cm; sincosf(0.5f * (phi - omega), &sm, &cm);
        smat[tid] = make_float4(cp * ct, -sp * ct, -cm * st, -sm * st);
    }
    __syncthreads();

    // product-state init, identity basis: k = (tid<<4)|l, bit p <-> wire 11-p
    float base = 1.0f;
    #pragma unroll
    for (int p = 4; p < NQ; p++) {
        int w = NQ - 1 - p;
        base *= ((tid >> (p - 4)) & 1) ? sss[w] : scs[w];
    }
    v2f Z[16];
    #pragma unroll
    for (int l = 0; l < 16; l++) {
        float a = base;
        #pragma unroll
        for (int p = 0; p < 4; p++) {
            int w = NQ - 1 - p;
            a *= ((l >> p) & 1) ? sss[w] : scs[w];
        }
        Z[l].x = a; Z[l].y = 0.0f;
    }

    do_layer<0>(Z, smat, xb, tid);
    do_layer<1>(Z, smat, xb, tid);
    do_layer<2>(Z, smat, xb, tid);
    do_layer<3>(Z, smat, xb, tid);
    do_layer<4>(Z, smat, xb, tid);
    do_layer<5>(Z, smat, xb, tid);

    // expectation: coef = b + sum_p W[11-p]*(1-2*bit_p(i(k)))
    const float bv = bptr[0];
    float wb[NQ];
    #pragma unroll
    for (int p = 0; p < NQ; p++) {
        uint32_t row = CK.frow[p];
        int tp = __popc(tid & (int)(row >> 4)) & 1;
        float Wv = Wp[NQ - 1 - p];
        wb[p] = tp ? -Wv : Wv;
    }
    float acc = 0.0f;
    #pragma unroll
    for (int l = 0; l < 16; l++) {
        float coef = bv;
        #pragma unroll
        for (int p = 0; p < NQ; p++)
            coef += (__popc(l & (int)(CK.frow[p] & 15u)) & 1) ? -wb[p] : wb[p];
        acc += (Z[l].x * Z[l].x + Z[l].y * Z[l].y) * coef;
    }
    #pragma unroll
    for (int off = 32; off > 0; off >>= 1)
        acc += __shfl_down(acc, off, 64);
    if ((tid & 63) == 0) red[tid >> 6] = acc;
    __syncthreads();
    if (tid == 0) out[b] = red[0] + red[1] + red[2] + red[3];
}

extern "C" void kernel_launch(void* const* d_in, const int* in_sizes, int n_in,
                              void* d_out, int out_size, void* d_ws, size_t ws_size,
                              hipStream_t stream) {
    const float* x       = (const float*)d_in[0];
    const float* weights = (const float*)d_in[1];
    const float* W       = (const float*)d_in[2];
    const float* bptr    = (const float*)d_in[3];
    qsim_kernel<<<512, TPB, 0, stream>>>(x, weights, W, bptr, (float*)d_out);
}